// Round 1
// baseline (532.634 us; speedup 1.0000x reference)
//
#include <hip/hip_runtime.h>

#define B_   32
#define N_   512
#define G_   64
#define T_   16
#define D_   256
#define E_   500000
#define M_   1024
#define TD_  (T_ * D_)          // 4096 floats between scope_type rows
#define NEG_ (-10000000000.0f)

// ---------------------------------------------------------------------------
// kernel 0: classify tree_mask storage. flag = 1 (bool bytes), 2 (float32),
// 0 (int32). Scans first 16384 bytes (in-bounds for all three encodings:
// bool buffer is exactly 16 KB; int32/float32 buffers are 64 KB).
// Little-endian: int32 0/1 has bytes 1..3 == 0; float32 0.0/1.0 has bytes
// 0..1 == 0 but byte 3 in {0, 0x3f}; bool data has ~70% ones everywhere.
// ---------------------------------------------------------------------------
__global__ __launch_bounds__(256) void detect_mask_dtype(
    const unsigned char* __restrict__ tm, int* __restrict__ flag) {
  __shared__ int sA, sB;
  if (threadIdx.x == 0) { sA = 0; sB = 0; }
  __syncthreads();
  int a = 0, b3 = 0;
  for (int i = threadIdx.x; i < B_ * N_; i += 256) {
    const int r = i & 3;
    const unsigned char v = tm[i];
    if (r == 1) a |= v;
    else if (r == 3) b3 |= v;
  }
  if (a)  atomicOr(&sA, 1);
  if (b3) atomicOr(&sB, 1);
  __syncthreads();
  if (threadIdx.x == 0) flag[0] = sA ? 1 : (sB ? 2 : 0);
}

// ---------------------------------------------------------------------------
// kernel 1: Wg[j][d] = sum_f W[d][f] * goal_type[j][f],  j in [0, 2048)
// One block = 8 goal rows; thread d streams W row d (float4), goal reads are
// wave-uniform -> scalar loads. 268 MFLOP total.
// ---------------------------------------------------------------------------
__global__ __launch_bounds__(256) void wg_gemm(
    const float* __restrict__ goal, const float* __restrict__ W,
    float* __restrict__ Wg) {
  const int j0 = blockIdx.x * 8;
  const int d  = threadIdx.x;
  float acc[8];
#pragma unroll
  for (int jj = 0; jj < 8; jj++) acc[jj] = 0.f;
  const float4* wrow = reinterpret_cast<const float4*>(W + (size_t)d * D_);
#pragma unroll 4
  for (int i = 0; i < D_ / 4; i++) {
    const float4 w4 = wrow[i];
#pragma unroll
    for (int jj = 0; jj < 8; jj++) {
      const float4 g4 = *reinterpret_cast<const float4*>(
          goal + (size_t)(j0 + jj) * TD_ + i * 4);
      acc[jj] = fmaf(w4.x, g4.x,
                fmaf(w4.y, g4.y,
                fmaf(w4.z, g4.z,
                fmaf(w4.w, g4.w, acc[jj]))));
    }
  }
#pragma unroll
  for (int jj = 0; jj < 8; jj++)
    Wg[(size_t)(j0 + jj) * D_ + d] = acc[jj];
}

// ---------------------------------------------------------------------------
// kernel 2: lemma_preds[e] = scope_type[src_e] . Wg[tgt_e] + bias
// Quarter-wave (16 lanes) per edge: each row read is 4 coalesced 256 B
// segments (16 lanes x float4), then a 4-step shuffle reduce.
// ---------------------------------------------------------------------------
__global__ __launch_bounds__(256) void lemma_kernel(
    const float* __restrict__ scope, const float* __restrict__ Wg,
    const int* __restrict__ edges, const float* __restrict__ bias,
    float* __restrict__ out) {
  const int lane = threadIdx.x & 63;
  const int sub  = lane >> 4;   // edge slot within wave (0..3)
  const int l    = lane & 15;   // lane within edge group
  const int gw   = (blockIdx.x * 256 + threadIdx.x) >> 6;  // global wave id
  const int e    = gw * 4 + sub;
  float acc = 0.f;
  if (e < E_) {
    const int s = edges[e];
    const int t = edges[E_ + e];
    const float4* sp = reinterpret_cast<const float4*>(scope + (size_t)s * TD_);
    const float4* wp = reinterpret_cast<const float4*>(Wg + (size_t)t * D_);
#pragma unroll
    for (int i = 0; i < 4; i++) {
      const float4 a = sp[l + i * 16];
      const float4 b = wp[l + i * 16];
      acc += a.x * b.x + a.y * b.y + a.z * b.z + a.w * b.w;
    }
  }
  acc += __shfl_xor(acc, 1);
  acc += __shfl_xor(acc, 2);
  acc += __shfl_xor(acc, 4);
  acc += __shfl_xor(acc, 8);
  if (l == 0 && e < E_) out[e] = acc + bias[0];
}

// ---------------------------------------------------------------------------
// kernel 3: lm_preds[m][n] = mask_reprs[m] . scope_type[batch_pts[m]][n],
// masked by tree_mask. Block = (b, 32-wide n-tile); candidate tile staged in
// LDS once, reused across all m with batch_pts[m]==b (uniform branch).
// Row pad 260 floats: k-sliced reads (8 lanes/n, 32-float stride) then cover
// all 32 banks at the structural minimum instead of one bank quad.
// ---------------------------------------------------------------------------
__global__ __launch_bounds__(256) void lm_kernel(
    const float* __restrict__ scope, const int* __restrict__ lm_idx,
    const int* __restrict__ batch_pts, const void* __restrict__ tree_mask,
    const int* __restrict__ flag_p, float* __restrict__ out) {
  __shared__ float cand[32][260];
  __shared__ unsigned char tmask[32];
  const int b  = blockIdx.x >> 4;
  const int n0 = (blockIdx.x & 15) * 32;
  const int t  = threadIdx.x;

  {  // stage candidate tile: 32 rows x 256 floats (coalesced 1 KB per row)
    const int lane = t & 63;
    const int r0   = t >> 6;  // 0..3
#pragma unroll
    for (int rr = 0; rr < 8; rr++) {
      const int row = rr * 4 + r0;
      const float4 v = *reinterpret_cast<const float4*>(
          scope + (size_t)(b * N_ + n0 + row) * TD_ + lane * 4);
      float* dst = &cand[row][lane * 4];
      dst[0] = v.x; dst[1] = v.y; dst[2] = v.z; dst[3] = v.w;
    }
  }
  const int flag = flag_p[0];
  if (t < 32) {
    const int n = b * N_ + n0 + t;
    int v;
    if (flag == 1)      v = ((const unsigned char*)tree_mask)[n] != 0;
    else if (flag == 2) v = ((const float*)tree_mask)[n] != 0.0f;
    else                v = ((const int*)tree_mask)[n] != 0;
    tmask[t] = (unsigned char)v;
  }
  __syncthreads();

  const int nl = t >> 3;  // local n (0..31)
  const int kg = t & 7;   // k-slice group (0..7), 32 floats each
  for (int m = 0; m < M_; m++) {
    if (batch_pts[m] != b) continue;  // wave-uniform branch
    const float4* q =
        reinterpret_cast<const float4*>(scope + (size_t)lm_idx[m] * D_);
    float acc = 0.f;
#pragma unroll
    for (int i = 0; i < 8; i++) {
      const int f4 = kg * 8 + i;
      const float4 qv = q[f4];
      const float* cp = &cand[nl][f4 * 4];
      acc += qv.x * cp[0] + qv.y * cp[1] + qv.z * cp[2] + qv.w * cp[3];
    }
    acc += __shfl_xor(acc, 1);
    acc += __shfl_xor(acc, 2);
    acc += __shfl_xor(acc, 4);
    if (kg == 0)
      out[(size_t)m * N_ + (n0 + nl)] = tmask[nl] ? acc : NEG_;
  }
}

// ---------------------------------------------------------------------------
extern "C" void kernel_launch(void* const* d_in, const int* in_sizes, int n_in,
                              void* d_out, int out_size, void* d_ws,
                              size_t ws_size, hipStream_t stream) {
  const float* scope = (const float*)d_in[0];  // (B,N,T,D) fp32
  const float* goal  = (const float*)d_in[1];  // (B,G,T,D) fp32
  const float* W     = (const float*)d_in[2];  // (1,D,D)   fp32
  const float* bias  = (const float*)d_in[3];  // (1,)      fp32
  const int*   edges = (const int*)d_in[4];    // (2,E)     int32
  const int*   lmidx = (const int*)d_in[5];    // (M,)      int32
  const int*   bpts  = (const int*)d_in[6];    // (M,)      int32
  const void*  tmask = d_in[7];                // (B,N)     bool/int32

  float* out  = (float*)d_out;                 // [lemma(E) | lm(M*N)]
  float* Wg   = (float*)d_ws;                  // 2048*256 fp32 = 2 MB
  int*   flag = (int*)((char*)d_ws + (size_t)2048 * 256 * 4);

  detect_mask_dtype<<<1, 256, 0, stream>>>((const unsigned char*)tmask, flag);
  wg_gemm<<<256, 256, 0, stream>>>(goal, W, Wg);
  lemma_kernel<<<31250, 256, 0, stream>>>(scope, Wg, edges, bias, out);
  lm_kernel<<<B_ * 16, 256, 0, stream>>>(scope, lmidx, bpts, tmask, flag,
                                         out + E_);
}

// Round 2
// 504.204 us; speedup vs baseline: 1.0564x; 1.0564x over previous
//
#include <hip/hip_runtime.h>

#define B_   32
#define N_   512
#define G_   64
#define T_   16
#define D_   256
#define E_   500000
#define M_   1024
#define TD_  (T_ * D_)          // 4096 floats between scope_type rows
#define NEG_ (-10000000000.0f)

// ---------------------------------------------------------------------------
// kernel 0: classify tree_mask storage. flag = 1 (bool bytes), 2 (float32),
// 0 (int32). (unchanged from R1 — verified working)
// ---------------------------------------------------------------------------
__global__ __launch_bounds__(256) void detect_mask_dtype(
    const unsigned char* __restrict__ tm, int* __restrict__ flag) {
  __shared__ int sA, sB;
  if (threadIdx.x == 0) { sA = 0; sB = 0; }
  __syncthreads();
  int a = 0, b3 = 0;
  for (int i = threadIdx.x; i < B_ * N_; i += 256) {
    const int r = i & 3;
    const unsigned char v = tm[i];
    if (r == 1) a |= v;
    else if (r == 3) b3 |= v;
  }
  if (a)  atomicOr(&sA, 1);
  if (b3) atomicOr(&sB, 1);
  __syncthreads();
  if (threadIdx.x == 0) flag[0] = sA ? 1 : (sB ? 2 : 0);
}

// ---------------------------------------------------------------------------
// kernel 1a: Wt[f][d] = W[d][f].  32x32 LDS tiles, +1 pad. 256 KB total.
// Both the read and the write are lane-contiguous.
// ---------------------------------------------------------------------------
__global__ __launch_bounds__(256) void transpose_w(
    const float* __restrict__ W, float* __restrict__ Wt) {
  __shared__ float tile[32][33];
  const int bi = blockIdx.x >> 3;   // d-tile
  const int bj = blockIdx.x & 7;    // f-tile
  const int tx = threadIdx.x & 31;
  const int ty = threadIdx.x >> 5;  // 0..7
#pragma unroll
  for (int r = 0; r < 4; r++) {
    const int d = bi * 32 + ty + r * 8;
    const int f = bj * 32 + tx;
    tile[ty + r * 8][tx] = W[(size_t)d * D_ + f];
  }
  __syncthreads();
#pragma unroll
  for (int r = 0; r < 4; r++) {
    const int f = bj * 32 + ty + r * 8;
    const int d = bi * 32 + tx;
    Wt[(size_t)f * D_ + d] = tile[tx][ty + r * 8];
  }
}

// ---------------------------------------------------------------------------
// kernel 1b: Wg[j][d] = sum_f goal_type[j][f] * Wt[f][d].
// Block = 8 goal rows staged in LDS (broadcast reads); thread d reads
// Wt[f][d] -> lane-contiguous 1 KB per instruction, Wt (256 KB) L2-resident.
// ---------------------------------------------------------------------------
__global__ __launch_bounds__(256) void wg_gemm(
    const float* __restrict__ goal, const float* __restrict__ Wt,
    float* __restrict__ Wg) {
  __shared__ float g[8][256];
  const int j0 = blockIdx.x * 8;
  const int d  = threadIdx.x;
  {
    const int lane = threadIdx.x & 63;
    const int r0   = threadIdx.x >> 6;  // 0..3
#pragma unroll
    for (int rr = 0; rr < 2; rr++) {
      const int row = rr * 4 + r0;
      const float4 v = *reinterpret_cast<const float4*>(
          goal + (size_t)(j0 + row) * TD_ + lane * 4);
      float* dst = &g[row][lane * 4];
      dst[0] = v.x; dst[1] = v.y; dst[2] = v.z; dst[3] = v.w;
    }
  }
  __syncthreads();
  float acc[8];
#pragma unroll
  for (int jj = 0; jj < 8; jj++) acc[jj] = 0.f;
#pragma unroll 4
  for (int f = 0; f < D_; f++) {
    const float w = Wt[(size_t)f * D_ + d];
#pragma unroll
    for (int jj = 0; jj < 8; jj++) acc[jj] = fmaf(g[jj][f], w, acc[jj]);
  }
#pragma unroll
  for (int jj = 0; jj < 8; jj++)
    Wg[(size_t)(j0 + jj) * D_ + d] = acc[jj];
}

// ---------------------------------------------------------------------------
// kernel 2: lemma_preds[e] = scope_type[src_e] . Wg[tgt_e] + bias
// (unchanged from R1 — attribution anchor; theoretically LLC-BW-bound)
// ---------------------------------------------------------------------------
__global__ __launch_bounds__(256) void lemma_kernel(
    const float* __restrict__ scope, const float* __restrict__ Wg,
    const int* __restrict__ edges, const float* __restrict__ bias,
    float* __restrict__ out) {
  const int lane = threadIdx.x & 63;
  const int sub  = lane >> 4;
  const int l    = lane & 15;
  const int gw   = (blockIdx.x * 256 + threadIdx.x) >> 6;
  const int e    = gw * 4 + sub;
  float acc = 0.f;
  if (e < E_) {
    const int s = edges[e];
    const int t = edges[E_ + e];
    const float4* sp = reinterpret_cast<const float4*>(scope + (size_t)s * TD_);
    const float4* wp = reinterpret_cast<const float4*>(Wg + (size_t)t * D_);
#pragma unroll
    for (int i = 0; i < 4; i++) {
      const float4 a = sp[l + i * 16];
      const float4 b = wp[l + i * 16];
      acc += a.x * b.x + a.y * b.y + a.z * b.z + a.w * b.w;
    }
  }
  acc += __shfl_xor(acc, 1);
  acc += __shfl_xor(acc, 2);
  acc += __shfl_xor(acc, 4);
  acc += __shfl_xor(acc, 8);
  if (l == 0 && e < E_) out[e] = acc + bias[0];
}

// ---------------------------------------------------------------------------
// kernel 3: lm_preds. R2 change: cooperative compaction of the matching-m
// list into LDS (coalesced scan, 4 loads/thread) replaces the 1024-iteration
// serial dependent-load scan per block.
// ---------------------------------------------------------------------------
__global__ __launch_bounds__(256) void lm_kernel(
    const float* __restrict__ scope, const int* __restrict__ lm_idx,
    const int* __restrict__ batch_pts, const void* __restrict__ tree_mask,
    const int* __restrict__ flag_p, float* __restrict__ out) {
  __shared__ float cand[32][260];
  __shared__ unsigned char tmask[32];
  __shared__ int mlist[M_];
  __shared__ int mcnt;
  const int b  = blockIdx.x >> 4;
  const int n0 = (blockIdx.x & 15) * 32;
  const int t  = threadIdx.x;

  if (t == 0) mcnt = 0;
  {  // stage candidate tile: 32 rows x 256 floats
    const int lane = t & 63;
    const int r0   = t >> 6;
#pragma unroll
    for (int rr = 0; rr < 8; rr++) {
      const int row = rr * 4 + r0;
      const float4 v = *reinterpret_cast<const float4*>(
          scope + (size_t)(b * N_ + n0 + row) * TD_ + lane * 4);
      float* dst = &cand[row][lane * 4];
      dst[0] = v.x; dst[1] = v.y; dst[2] = v.z; dst[3] = v.w;
    }
  }
  const int flag = flag_p[0];
  if (t < 32) {
    const int n = b * N_ + n0 + t;
    int v;
    if (flag == 1)      v = ((const unsigned char*)tree_mask)[n] != 0;
    else if (flag == 2) v = ((const float*)tree_mask)[n] != 0.0f;
    else                v = ((const int*)tree_mask)[n] != 0;
    tmask[t] = (unsigned char)v;
  }
  __syncthreads();

  // coalesced scan + LDS compaction (order within mlist is irrelevant:
  // each m writes a distinct output row)
#pragma unroll
  for (int c = 0; c < M_ / 256; c++) {
    const int m = c * 256 + t;
    if (batch_pts[m] == b) {
      const int p = atomicAdd(&mcnt, 1);
      mlist[p] = m;
    }
  }
  __syncthreads();
  const int cnt = mcnt;

  const int nl = t >> 3;  // local n (0..31)
  const int kg = t & 7;   // k-slice group (0..7), 32 floats each
  for (int k = 0; k < cnt; k++) {
    const int m = mlist[k];
    const float4* q =
        reinterpret_cast<const float4*>(scope + (size_t)lm_idx[m] * D_);
    float acc = 0.f;
#pragma unroll
    for (int i = 0; i < 8; i++) {
      const int f4 = kg * 8 + i;
      const float4 qv = q[f4];
      const float* cp = &cand[nl][f4 * 4];
      acc += qv.x * cp[0] + qv.y * cp[1] + qv.z * cp[2] + qv.w * cp[3];
    }
    acc += __shfl_xor(acc, 1);
    acc += __shfl_xor(acc, 2);
    acc += __shfl_xor(acc, 4);
    if (kg == 0)
      out[(size_t)m * N_ + (n0 + nl)] = tmask[nl] ? acc : NEG_;
  }
}

// ---------------------------------------------------------------------------
extern "C" void kernel_launch(void* const* d_in, const int* in_sizes, int n_in,
                              void* d_out, int out_size, void* d_ws,
                              size_t ws_size, hipStream_t stream) {
  const float* scope = (const float*)d_in[0];  // (B,N,T,D) fp32
  const float* goal  = (const float*)d_in[1];  // (B,G,T,D) fp32
  const float* W     = (const float*)d_in[2];  // (1,D,D)   fp32
  const float* bias  = (const float*)d_in[3];  // (1,)      fp32
  const int*   edges = (const int*)d_in[4];    // (2,E)     int32
  const int*   lmidx = (const int*)d_in[5];    // (M,)      int32
  const int*   bpts  = (const int*)d_in[6];    // (M,)      int32
  const void*  tmask = d_in[7];                // (B,N)     bool/int32

  float* out  = (float*)d_out;                 // [lemma(E) | lm(M*N)]
  float* Wg   = (float*)d_ws;                  // 2048*256 fp32 = 2 MB
  float* Wt   = (float*)((char*)d_ws + (size_t)2048 * 256 * 4);  // 256 KB
  int*   flag = (int*)((char*)d_ws + (size_t)2048 * 256 * 4 + (size_t)D_ * D_ * 4);

  detect_mask_dtype<<<1, 256, 0, stream>>>((const unsigned char*)tmask, flag);
  transpose_w<<<64, 256, 0, stream>>>(W, Wt);
  wg_gemm<<<256, 256, 0, stream>>>(goal, Wt, Wg);
  lemma_kernel<<<31250, 256, 0, stream>>>(scope, Wg, edges, bias, out);
  lm_kernel<<<B_ * 16, 256, 0, stream>>>(scope, lmidx, bpts, tmask, flag,
                                         out + E_);
}